// Round 9
// baseline (151.903 us; speedup 1.0000x reference)
//
#include <hip/hip_runtime.h>

typedef _Float16 f16;
typedef _Float16 f16x8 __attribute__((ext_vector_type(8)));
typedef float f32x4 __attribute__((ext_vector_type(4)));

// Prefix table over the 225 (dx,dy) groups; each group contributes
// ceil(cx*cy/2) blocks of 2 pairs. Total = (4096 + 64)/2 = 2080 blocks.
struct Pref { int v[226]; };
constexpr Pref make_pref() {
    Pref t{};
    int acc = 0;
    for (int g = 0; g < 225; ++g) {
        t.v[g] = acc;
        const int dx = g / 15, dy = g % 15;
        const int cx = 8 - (dx < 7 ? 7 - dx : dx - 7);
        const int cy = 8 - (dy < 7 ? 7 - dy : dy - 7);
        acc += (cx * cy + 1) / 2;
    }
    t.v[225] = acc;   // 2080
    return t;
}
__constant__ Pref c_pref = make_pref();

// Single fused kernel. Block = 256 thr = 4 waves, handles 2 (x,y,X,Y) pairs
// of one (dx,dy) group; W[dxdy] staged fp32->f16 into LDS once per block.
// Wave = (pair = w>>1, tile-set = w&1): 4 b-tiles of 16 per wave -> each
// bfrag ds_read_b128 feeds 4 MFMA; no inter-wave exchange, 1 barrier.
// LDS layout [i][o][quad][8] halves: every wave-level LDS op (staging writes
// and K-loop reads) covers a contiguous 1024 B region -> conflict-free.
__global__ __launch_bounds__(256, 4) void rel_fused2(
    const float* __restrict__ inp,   // (128,8,8,32)
    const float* __restrict__ W,     // (15,15,16,32,32) [dx][dy][o][i][j]
    const float* __restrict__ bias,  // (15,15,16)
    float* __restrict__ out)         // (128,8,8,8,8,16)
{
    extern __shared__ __align__(16) f16 Wl[];   // 32768 B exactly

    const int bid = blockIdx.x;
    // ---- binary search: group g with pref[g] <= bid < pref[g+1] ----
    int lo = 0, hi = 225;
    #pragma unroll
    for (int s = 0; s < 8; ++s) {
        const int mid = (lo + hi) >> 1;
        if (c_pref.v[mid] <= bid) lo = mid; else hi = mid;
    }
    const int g = lo;
    const int p0 = (bid - c_pref.v[g]) * 2;
    const int dx = g / 15, dy = g % 15;
    const int cx = 8 - (dx < 7 ? 7 - dx : dx - 7);
    const int cy = 8 - (dy < 7 ? 7 - dy : dy - 7);
    const int npairs = cx * cy;

    const int t = threadIdx.x;

    // ---- stage W[g] fp32 -> f16 -> LDS [i][o][quad][8] ----
    // granule r = it*256 + t: i=r>>6, o=(r>>2)&15, quad=r&3;
    // per-instr the wave covers granules [it*256+wave*64, +64) = 1024 B contig.
    {
        const float* Wg = W + (size_t)g * 16384;
        #pragma unroll
        for (int half = 0; half < 2; ++half) {
            float4 v[8];
            int rr[4];
            #pragma unroll
            for (int q = 0; q < 4; ++q) {
                const int r = (half * 4 + q) * 256 + t;
                rr[q] = r;
                const int i = r >> 6, o = (r >> 2) & 15, quad = r & 3;
                const float* src = Wg + o * 1024 + i * 32 + quad * 8;
                v[2 * q]     = ((const float4*)src)[0];
                v[2 * q + 1] = ((const float4*)src)[1];
            }
            #pragma unroll
            for (int q = 0; q < 4; ++q) {
                const f16x8 h = { (f16)v[2*q].x,   (f16)v[2*q].y,
                                  (f16)v[2*q].z,   (f16)v[2*q].w,
                                  (f16)v[2*q+1].x, (f16)v[2*q+1].y,
                                  (f16)v[2*q+1].z, (f16)v[2*q+1].w };
                *(f16x8*)(&Wl[rr[q] * 8]) = h;
            }
        }
    }

    const int lane = t & 63;
    const int wave = t >> 6;        // 0..3
    const int pairw = wave >> 1;    // pair p0 + pairw
    const int tset = wave & 1;      // b-tiles tset*4 .. +3
    const int quad = lane >> 4;
    const int m = lane & 15;        // A-row (b%16) and B-col (o)

    // ---- this wave's pair -> (x,y,X,Y) ----
    const int ppair = p0 + pairw;
    const bool valid = ppair < npairs;
    const int p = valid ? ppair : (npairs - 1);
    const int ix = p / cy, iy = p - ix * cy;
    const int x = (dx < 7 ? 7 - dx : 0) + ix;
    const int y = (dy < 7 ? 7 - dy : 0) + iy;
    const int X = x + dx - 7, Y = y + dy - 7;

    // ---- a-rows + c-frags for 4 b-tiles, fp32 -> f16 (overlaps staging) ----
    f16x8 a[4][4], c[4];
    #pragma unroll
    for (int tt = 0; tt < 4; ++tt) {
        const int b = (tset * 4 + tt) * 16 + m;
        const float* ar = inp + ((b * 8 + x) * 8 + y) * 32;
        #pragma unroll
        for (int gg = 0; gg < 4; ++gg) {
            const float4 u0 = *(const float4*)(ar + gg * 8);
            const float4 u1 = *(const float4*)(ar + gg * 8 + 4);
            a[tt][gg] = f16x8{ (f16)u0.x, (f16)u0.y, (f16)u0.z, (f16)u0.w,
                               (f16)u1.x, (f16)u1.y, (f16)u1.z, (f16)u1.w };
        }
        const float* cr = inp + ((b * 8 + X) * 8 + Y) * 32 + quad * 8;
        const float4 w0 = *(const float4*)cr;
        const float4 w1 = *(const float4*)(cr + 4);
        c[tt] = f16x8{ (f16)w0.x, (f16)w0.y, (f16)w0.z, (f16)w0.w,
                       (f16)w1.x, (f16)w1.y, (f16)w1.z, (f16)w1.w };
    }

    __syncthreads();

    // ---- K-loop: 32 steps (kb = i); bfrag shared by 4 b-tiles ----
    f32x4 acc[4] = { {0,0,0,0}, {0,0,0,0}, {0,0,0,0}, {0,0,0,0} };
    const f16* wl = &Wl[m * 32 + quad * 8];
    f16x8 bfrag = *(const f16x8*)(wl);
    #pragma unroll
    for (int kb = 0; kb < 32; ++kb) {
        const f16x8 bcur = bfrag;
        if (kb < 31)
            bfrag = *(const f16x8*)(wl + (kb + 1) * 512);   // prefetch next i
        #pragma unroll
        for (int tt = 0; tt < 4; ++tt) {
            const f16x8 af = c[tt] * a[tt][kb >> 3][kb & 7]; // P[b, kb*32+quad*8+r]
            acc[tt] = __builtin_amdgcn_mfma_f32_16x16x32_f16(af, bcur, acc[tt], 0, 0, 0);
        }
    }

    // ---- epilogue: D[row = b%16 = quad*4+r, col = o = m] ----
    if (valid) {
        const float bv = bias[g * 16 + m];
        const size_t pos = (size_t)(x * 512 + y * 64 + X * 8 + Y);
        #pragma unroll
        for (int tt = 0; tt < 4; ++tt) {
            #pragma unroll
            for (int r = 0; r < 4; ++r) {
                const int b = (tset * 4 + tt) * 16 + quad * 4 + r;
                out[((size_t)b * 4096 + pos) * 16 + m] = acc[tt][r] + bv;
            }
        }
    }
}

extern "C" void kernel_launch(void* const* d_in, const int* in_sizes, int n_in,
                              void* d_out, int out_size, void* d_ws, size_t ws_size,
                              hipStream_t stream)
{
    const float* inp  = (const float*)d_in[0];  // (128,8,8,32)
    const float* W    = (const float*)d_in[1];  // (15,15,16,32,32)
    const float* bias = (const float*)d_in[2];  // (15,15,16)
    float* out = (float*)d_out;

    hipLaunchKernelGGL(rel_fused2, dim3(2080), dim3(256), 32768, stream,
                       inp, W, bias, out);
}

// Round 10
// 107.728 us; speedup vs baseline: 1.4101x; 1.4101x over previous
//
#include <hip/hip_runtime.h>

typedef _Float16 f16;
typedef _Float16 f16x8 __attribute__((ext_vector_type(8)));
typedef float f32x4 __attribute__((ext_vector_type(4)));
typedef unsigned int u32;
typedef const __attribute__((address_space(1))) u32* gas1_t;
typedef __attribute__((address_space(3))) u32* las3_t;

#define WGRAN 460800   // 225 * 2048 granules of 8 halves (W)
#define IGRAN 32768    // 262144/8 granules (inp)

// fp32 -> f16 with W permuted into the fragment-ready layout:
// W_h[dxdy][i][o][quad] (granules of 8 halves) = W[dxdy][o][i][quad*8+u]
__global__ __launch_bounds__(256) void convert_kernel(
    const float* __restrict__ W, const float* __restrict__ inp,
    f16* __restrict__ W_h, f16* __restrict__ inp_h)
{
    const int g = blockIdx.x * 256 + threadIdx.x;   // grid sized exactly
    if (g < WGRAN) {
        const int dxdy = g >> 11;
        const int r = g & 2047;
        const int i = r >> 6, o = (r >> 2) & 15, quad = r & 3;
        const float* src = W + (size_t)dxdy * 16384 + o * 1024 + i * 32 + quad * 8;
        const float4 v0 = *(const float4*)src;
        const float4 v1 = *(const float4*)(src + 4);
        f16x8 h = { (f16)v0.x, (f16)v0.y, (f16)v0.z, (f16)v0.w,
                    (f16)v1.x, (f16)v1.y, (f16)v1.z, (f16)v1.w };
        *(f16x8*)(W_h + (size_t)g * 8) = h;
    } else {
        const int k = g - WGRAN;
        const float* src = inp + (size_t)k * 8;
        const float4 v0 = *(const float4*)src;
        const float4 v1 = *(const float4*)(src + 4);
        f16x8 h = { (f16)v0.x, (f16)v0.y, (f16)v0.z, (f16)v0.w,
                    (f16)v1.x, (f16)v1.y, (f16)v1.z, (f16)v1.w };
        *(f16x8*)(inp_h + (size_t)k * 8) = h;
    }
}

// Prefix table over the 225 (dx,dy) groups; each group contributes
// ceil(cx*cy/2) blocks of 2 pairs. Total = 2080 blocks.
struct Pref { int v[226]; };
constexpr Pref make_pref() {
    Pref t{};
    int acc = 0;
    for (int g = 0; g < 225; ++g) {
        t.v[g] = acc;
        const int dx = g / 15, dy = g % 15;
        const int cx = 8 - (dx < 7 ? 7 - dx : dx - 7);
        const int cy = 8 - (dy < 7 ? 7 - dy : dy - 7);
        acc += (cx * cy + 1) / 2;
    }
    t.v[225] = acc;   // 2080
    return t;
}
__constant__ Pref c_pref = make_pref();

// Block = 256 thr = 4 waves, 2 pairs of one (dx,dy) group, W_h staged once
// via global_load_lds. Wave = (pair = w>>1, tile-set = w&1): 4 b-tiles/wave
// -> 4 MFMA per bfrag ds_read_b128. launch_bounds(256,3): 168-VGPR cap so
// the a[4][4] footprint does NOT spill (R9's VGPR=64 + scratch was the bug).
__global__ __launch_bounds__(256, 3) void rel_fused3(
    const f16* __restrict__ W_h,    // [dxdy][i][o][quad][8]
    const f16* __restrict__ inp_h,  // (128,8,8,32) f16
    const float* __restrict__ bias, // (15,15,16)
    float* __restrict__ out)        // (128,8,8,8,8,16)
{
    extern __shared__ __align__(16) f16 Wl[];   // 32768 B exactly

    const int bid = blockIdx.x;
    // ---- binary search: group g with pref[g] <= bid < pref[g+1] ----
    int lo = 0, hi = 225;
    #pragma unroll
    for (int s = 0; s < 8; ++s) {
        const int mid = (lo + hi) >> 1;
        if (c_pref.v[mid] <= bid) lo = mid; else hi = mid;
    }
    const int g = lo;
    const int p0 = (bid - c_pref.v[g]) * 2;
    const int dx = g / 15, dy = g % 15;
    const int cx = 8 - (dx < 7 ? 7 - dx : dx - 7);
    const int cy = 8 - (dy < 7 ? 7 - dy : dy - 7);
    const int npairs = cx * cy;

    const int t = threadIdx.x;

    // ---- stage W_h[g] -> LDS via global_load_lds width=16 ----
    {
        const f16* base = W_h + (size_t)g * 16384;
        #pragma unroll
        for (int it = 0; it < 8; ++it) {
            const int idx = (it * 256 + t) * 8;          // 16 B granule
            __builtin_amdgcn_global_load_lds((gas1_t)(base + idx),
                                             (las3_t)&Wl[idx], 16, 0, 0);
        }
    }

    const int lane = t & 63;
    const int wave = t >> 6;        // 0..3
    const int pairw = wave >> 1;    // pair p0 + pairw
    const int tset = wave & 1;      // b-tiles tset*4 .. +3
    const int quad = lane >> 4;
    const int m = lane & 15;        // A-row (b%16) and B-col (o)

    // ---- this wave's pair -> (x,y,X,Y) ----
    const int ppair = p0 + pairw;
    const bool valid = ppair < npairs;
    const int p = valid ? ppair : (npairs - 1);
    const int ix = p / cy, iy = p - ix * cy;
    const int x = (dx < 7 ? 7 - dx : 0) + ix;
    const int y = (dy < 7 ? 7 - dy : 0) + iy;
    const int X = x + dx - 7, Y = y + dy - 7;

    // ---- a-rows + c-frags for 4 b-tiles from f16 inp (overlaps DMA) ----
    f16x8 a[4][4], c[4];
    #pragma unroll
    for (int tt = 0; tt < 4; ++tt) {
        const int b = (tset * 4 + tt) * 16 + m;
        const f16* ar = inp_h + ((b * 8 + x) * 8 + y) * 32;
        #pragma unroll
        for (int gg = 0; gg < 4; ++gg)
            a[tt][gg] = *(const f16x8*)(ar + gg * 8);
        c[tt] = *(const f16x8*)(inp_h + ((b * 8 + X) * 8 + Y) * 32 + quad * 8);
    }

    __syncthreads();   // drains vmcnt -> LDS DMA complete

    // ---- K-loop: 32 steps (kb = i); bfrag shared by 4 b-tiles ----
    f32x4 acc[4] = { {0,0,0,0}, {0,0,0,0}, {0,0,0,0}, {0,0,0,0} };
    const f16* wl = &Wl[m * 32 + quad * 8];
    f16x8 bfrag = *(const f16x8*)(wl);
    #pragma unroll
    for (int kb = 0; kb < 32; ++kb) {
        const f16x8 bcur = bfrag;
        if (kb < 31)
            bfrag = *(const f16x8*)(wl + (kb + 1) * 512);   // prefetch next i
        #pragma unroll
        for (int tt = 0; tt < 4; ++tt) {
            const f16x8 af = c[tt] * a[tt][kb >> 3][kb & 7]; // P[b, kb*32+quad*8+r]
            acc[tt] = __builtin_amdgcn_mfma_f32_16x16x32_f16(af, bcur, acc[tt], 0, 0, 0);
        }
    }

    // ---- epilogue: D[row = b%16 = quad*4+r, col = o = m] ----
    if (valid) {
        const float bv = bias[g * 16 + m];
        const size_t pos = (size_t)(x * 512 + y * 64 + X * 8 + Y);
        #pragma unroll
        for (int tt = 0; tt < 4; ++tt) {
            #pragma unroll
            for (int r = 0; r < 4; ++r) {
                const int b = (tset * 4 + tt) * 16 + quad * 4 + r;
                out[((size_t)b * 4096 + pos) * 16 + m] = acc[tt][r] + bv;
            }
        }
    }
}

extern "C" void kernel_launch(void* const* d_in, const int* in_sizes, int n_in,
                              void* d_out, int out_size, void* d_ws, size_t ws_size,
                              hipStream_t stream)
{
    const float* inp  = (const float*)d_in[0];  // (128,8,8,32)
    const float* W    = (const float*)d_in[1];  // (15,15,16,32,32)
    const float* bias = (const float*)d_in[2];  // (15,15,16)
    float* out = (float*)d_out;

    f16* W_h   = (f16*)d_ws;                         // 7,372,800 halves
    f16* inp_h = (f16*)d_ws + (size_t)WGRAN * 8;     //   262,144 halves

    hipLaunchKernelGGL(convert_kernel, dim3((WGRAN + IGRAN) / 256), dim3(256), 0,
                       stream, W, inp, W_h, inp_h);
    hipLaunchKernelGGL(rel_fused3, dim3(2080), dim3(256), 32768, stream,
                       W_h, inp_h, bias, out);
}